// Round 8
// baseline (321.525 us; speedup 1.0000x reference)
//
#include <hip/hip_runtime.h>
#include <hip/hip_bf16.h>

// ---------------------------------------------------------------------------
// SimplifiedGATBlock: 2-layer GAT, N=50000, E=800000 (+self loops)
// R8 = R7 + (1) persistent balanced agg waves (2 node-quads/wave, 1563 blocks,
// launch_bounds(256,6)) attacking the 36.6% occupancy / latency-bound agg;
// (2) gemm2+alpha2 fused (cheap ps[4] epilogue); (3) single-block scan.
// 7 launches.
// ---------------------------------------------------------------------------

typedef _Float16 half2_t __attribute__((ext_vector_type(2)));
typedef _Float16 half4_t __attribute__((ext_vector_type(4)));
typedef _Float16 f16x8 __attribute__((ext_vector_type(8)));
typedef float f32x4 __attribute__((ext_vector_type(4)));

#define NBLK1 128      // edge chunks for binning
#define SORT_CAP 6144  // per-bucket LDS sort capacity (avg ~4340, 13+ sigma)

static __device__ __forceinline__ float leaky02(float x) {
    return x > 0.f ? x : 0.2f * x;
}
static __device__ __forceinline__ float elu1(float x) {
    return x > 0.f ? x : __expf(x) - 1.f;
}

// ---------------- prep: bucket histogram + W1/W2 fp16 transpose ------------

__global__ __launch_bounds__(256) void prep_kernel(
    const int* __restrict__ dst, int* __restrict__ g_cnt, int E, int chunk,
    const float* __restrict__ W1, const float* __restrict__ W2,
    _Float16* __restrict__ Wt1, _Float16* __restrict__ Wt2, int nbkt) {
    int b = blockIdx.x;
    int t = threadIdx.x;
    if (b < NBLK1) {
        __shared__ int h[256];
        h[t] = 0;
        __syncthreads();
        int lo = b * chunk, hi = min(E, lo + chunk);
        for (int i = lo + t; i < hi; i += 256) atomicAdd(&h[dst[i] >> 8], 1);
        __syncthreads();
        if (t < nbkt) g_cnt[t * NBLK1 + b] = h[t];
    } else {
        int idx = (b - NBLK1) * 256 + t;  // 0..32767
        int which = idx >> 14;
        int r = idx & 16383;
        int nc = r >> 7, k = r & 127;
        if (which == 0)
            Wt1[(size_t)nc * 128 + k] = (_Float16)W1[(size_t)k * 128 + nc];
        else
            Wt2[(size_t)nc * 128 + k] = (_Float16)W2[(size_t)k * 128 + nc];
    }
}

// ---------------- single-block exclusive scan: offs[0..ncnt] ---------------

__global__ __launch_bounds__(256) void scan_one_kernel(const int* __restrict__ g_cnt,
                                                       int* __restrict__ offs, int ncnt) {
    __shared__ int ssum[256];
    int t = threadIdx.x;
    int per = (ncnt + 255) / 256;
    int lo = t * per, hi = min(ncnt, lo + per);
    int s = 0;
    for (int i = lo; i < hi; ++i) s += g_cnt[i];
    ssum[t] = s;
    __syncthreads();
    for (int off = 1; off < 256; off <<= 1) {
        int u = (t >= off) ? ssum[t - off] : 0;
        __syncthreads();
        ssum[t] += u;
        __syncthreads();
    }
    int run = ssum[t] - s;  // exclusive prefix of this thread's chunk
    for (int i = lo; i < hi; ++i) {
        offs[i] = run;
        run += g_cnt[i];
    }
    if (t == 255) offs[ncnt] = run;
}

// ---------------- fused: MFMA gemm1 + bin scatter (no global atomics) ------

__global__ __launch_bounds__(256) void gemm1_fused_kernel(
    const float* __restrict__ X, const _Float16* __restrict__ Wt,
    _Float16* __restrict__ H16, int nrows, const int* __restrict__ src,
    const int* __restrict__ dst, const int* __restrict__ offs,
    int* __restrict__ binned, int E, int chunk, int nGemm, int nbkt) {
    int b = blockIdx.x;
    int t = threadIdx.x;
    if (b < nGemm) {
        int wave = t >> 6, lane = t & 63;
        int m = lane & 15, q = lane >> 4;
        int arow = b * 64 + wave * 16 + m;
        bool rowok = arow < nrows;
        const float* xr = X + (size_t)arow * 128;
        f16x8 afrag[4];
#pragma unroll
        for (int s = 0; s < 4; ++s) {
            float4 v0 = make_float4(0.f, 0.f, 0.f, 0.f);
            float4 v1 = make_float4(0.f, 0.f, 0.f, 0.f);
            if (rowok) {
                v0 = *(const float4*)(xr + s * 32 + q * 8);
                v1 = *(const float4*)(xr + s * 32 + q * 8 + 4);
            }
            f16x8 a;
            a[0] = (_Float16)v0.x; a[1] = (_Float16)v0.y;
            a[2] = (_Float16)v0.z; a[3] = (_Float16)v0.w;
            a[4] = (_Float16)v1.x; a[5] = (_Float16)v1.y;
            a[6] = (_Float16)v1.z; a[7] = (_Float16)v1.w;
            afrag[s] = a;
        }
#pragma unroll
        for (int c = 0; c < 8; ++c) {
            f32x4 acc = {0.f, 0.f, 0.f, 0.f};
#pragma unroll
            for (int s = 0; s < 4; ++s) {
                f16x8 bfrag = *(const f16x8*)(Wt + (size_t)(c * 16 + m) * 128 + s * 32 + q * 8);
                acc = __builtin_amdgcn_mfma_f32_16x16x32_f16(afrag[s], bfrag, acc, 0, 0, 0);
            }
#pragma unroll
            for (int r = 0; r < 4; ++r) {
                int orow = b * 64 + wave * 16 + q * 4 + r;
                if (orow < nrows)
                    H16[(size_t)orow * 128 + c * 16 + m] = (_Float16)acc[r];
            }
        }
    } else {
        __shared__ int cur[256];
        int sb = b - nGemm;  // 0..NBLK1-1
        if (t < nbkt) cur[t] = offs[t * NBLK1 + sb];
        __syncthreads();
        int lo = sb * chunk, hi = min(E, lo + chunk);
        for (int i = lo + t; i < hi; i += 256) {
            int d = dst[i];
            int s = src[i];
            int p = atomicAdd(&cur[d >> 8], 1);  // LDS atomic: disjoint global range
            binned[p] = ((d & 255) << 16) | s;   // N < 2^16: src fits 16 bits
        }
    }
}

// ---------------- fused: per-bucket LDS counting sort + alpha1 -------------

__global__ __launch_bounds__(256) void sort_alpha1_kernel(
    const int* __restrict__ binned, const int* __restrict__ offs,
    int* __restrict__ row_ptr, int* __restrict__ csr, int n, int nbkt,
    const _Float16* __restrict__ H16, const float* __restrict__ a_src,
    const float* __restrict__ a_dst, float* __restrict__ asrc_out,
    float* __restrict__ adst_out) {
    int b = blockIdx.x;
    int t = threadIdx.x;
    if (b < nbkt) {
        __shared__ int sorted[SORT_CAP];
        __shared__ int sdata[256];
        __shared__ int cur[256];
        int estart = offs[b * NBLK1];
        int eend = offs[(b + 1) * NBLK1];
        int node0 = b * 256;
        int nloc = min(256, n - node0);
        cur[t] = (t < nloc) ? 1 : 0;  // self-loop seed
        __syncthreads();
        for (int i = estart + t; i < eend; i += 256)
            atomicAdd(&cur[(binned[i] >> 16) & 255], 1);
        __syncthreads();
        int my = cur[t];
        sdata[t] = my;
        __syncthreads();
        for (int off = 1; off < 256; off <<= 1) {
            int u = (t >= off) ? sdata[t - off] : 0;
            __syncthreads();
            sdata[t] += u;
            __syncthreads();
        }
        int excl = sdata[t] - my;
        int total = sdata[255];
        int csr_base = estart + node0;  // earlier buckets full: +256 selfs each
        if (node0 + t <= n) row_ptr[node0 + t] = csr_base + excl;
        if (t == 0 && node0 + 256 <= n) row_ptr[node0 + 256] = csr_base + total;
        if (t < nloc) {
            if (excl < SORT_CAP) sorted[excl] = node0 + t;  // self loop
            else csr[csr_base + excl] = node0 + t;
            cur[t] = excl + 1;
        } else {
            cur[t] = 0;
        }
        __syncthreads();
        for (int i = estart + t; i < eend; i += 256) {
            int v = binned[i];
            int p = atomicAdd(&cur[(v >> 16) & 255], 1);
            int sv = v & 0xffff;
            if (p < SORT_CAP) sorted[p] = sv;
            else csr[csr_base + p] = sv;  // overflow fallback (near-impossible)
        }
        __syncthreads();
        int lim = min(total, SORT_CAP);
        for (int j = t; j < lim; j += 256) csr[csr_base + j] = sorted[j];
    } else {
        int node = (b - nbkt) * 4 + (t >> 6);
        int lane = t & 63;
        if (node >= n) return;
        int c = lane * 2;
        half2_t hv = *(const half2_t*)(H16 + (size_t)node * 128 + c);
        float2 as = *(const float2*)(a_src + c);
        float2 ad = *(const float2*)(a_dst + c);
        float hx = (float)hv.x, hy = (float)hv.y;
        float ps = hx * as.x + hy * as.y;
        float pd = hx * ad.x + hy * ad.y;
#pragma unroll
        for (int off = 1; off <= 8; off <<= 1) {
            ps += __shfl_xor(ps, off, 64);
            pd += __shfl_xor(pd, off, 64);
        }
        if ((lane & 15) == 0) {
            int h = lane >> 4;
            asrc_out[node * 4 + h] = ps;
            adst_out[node * 4 + h] = pd;
        }
    }
}

// ---------------- fused: MFMA gemm2 + alpha2 epilogue ----------------

__global__ __launch_bounds__(256) void gemm2_fused_kernel(
    const _Float16* __restrict__ A16, const _Float16* __restrict__ Wt,
    _Float16* __restrict__ H16, int nrows, const float* __restrict__ a_src,
    const float* __restrict__ a_dst, float* __restrict__ asrc_out,
    float* __restrict__ adst_out) {
    int b = blockIdx.x;
    int t = threadIdx.x;
    int wave = t >> 6, lane = t & 63;
    int m = lane & 15, q = lane >> 4;
    int arow = b * 64 + wave * 16 + m;
    bool rowok = arow < nrows;
    const _Float16* ar = A16 + (size_t)arow * 128;
    f16x8 afrag[4];
#pragma unroll
    for (int s = 0; s < 4; ++s) {
        f16x8 a = {};
        if (rowok) a = *(const f16x8*)(ar + s * 32 + q * 8);
        afrag[s] = a;
    }
    float ps[4] = {0.f, 0.f, 0.f, 0.f};
    float pd[4] = {0.f, 0.f, 0.f, 0.f};
#pragma unroll
    for (int c = 0; c < 8; ++c) {
        f32x4 acc = {0.f, 0.f, 0.f, 0.f};
#pragma unroll
        for (int s = 0; s < 4; ++s) {
            f16x8 bfrag = *(const f16x8*)(Wt + (size_t)(c * 16 + m) * 128 + s * 32 + q * 8);
            acc = __builtin_amdgcn_mfma_f32_16x16x32_f16(afrag[s], bfrag, acc, 0, 0, 0);
        }
        float asv = a_src[c * 16 + m];
        float adv = a_dst[c * 16 + m];
#pragma unroll
        for (int r = 0; r < 4; ++r) {
            ps[r] += acc[r] * asv;
            pd[r] += acc[r] * adv;
            int orow = b * 64 + wave * 16 + q * 4 + r;
            if (orow < nrows)
                H16[(size_t)orow * 128 + c * 16 + m] = (_Float16)acc[r];
        }
    }
#pragma unroll
    for (int r = 0; r < 4; ++r) {
        float v = ps[r], u = pd[r];
#pragma unroll
        for (int off = 1; off <= 8; off <<= 1) {
            v += __shfl_xor(v, off, 64);
            u += __shfl_xor(u, off, 64);
        }
        ps[r] = v; pd[r] = u;
    }
    if (m == 0) {
#pragma unroll
        for (int r = 0; r < 4; ++r) {
            int row = b * 64 + wave * 16 + q * 4 + r;
            if (row < nrows) {
                asrc_out[row] = ps[r];
                adst_out[row] = pd[r];
            }
        }
    }
}

// ---------------- softmax aggregation ----------------
// Persistent balanced waves: every wave owns exactly 2 node-quads (8 nodes).
// 16-lane group per node; lane owns 8 channels (half8, 16B).

__global__ __launch_bounds__(256, 6) void agg1_kernel(
    const _Float16* __restrict__ H16, const float* __restrict__ asrc,
    const float* __restrict__ adst, const int* __restrict__ row_ptr,
    const int* __restrict__ csr, const float* __restrict__ bias,
    _Float16* __restrict__ out16, int n) {
    int wid = (blockIdx.x * blockDim.x + threadIdx.x) >> 6;
    int lane = threadIdx.x & 63;
    int sub = lane & 15;
    int c = sub * 8;
    int h = sub >> 2;  // head = c >> 5
    float4 bv0 = *(const float4*)(bias + c);
    float4 bv1 = *(const float4*)(bias + c + 4);
#pragma unroll
    for (int qq = 0; qq < 2; ++qq) {
        int node = wid * 8 + qq * 4 + (lane >> 4);
        if (node >= n) continue;
        float adh = adst[node * 4 + h];
        int e0 = row_ptr[node];
        int e1 = row_ptr[node + 1];
        float den = 0.f;
        float a[8];
#pragma unroll
        for (int k = 0; k < 8; ++k) a[k] = 0.f;
        int e = e0;
        for (; e + 8 <= e1; e += 8) {
            int s[8];
#pragma unroll
            for (int j = 0; j < 8; ++j) s[j] = csr[e + j];
            float l[8];
            f16x8 g[8];
#pragma unroll
            for (int j = 0; j < 8; ++j) {
                l[j] = asrc[s[j] * 4 + h];
                g[j] = *(const f16x8*)(H16 + (size_t)s[j] * 128 + c);
            }
#pragma unroll
            for (int j = 0; j < 8; ++j) {
                float w = __expf(leaky02(l[j] + adh));
                den += w;
#pragma unroll
                for (int k = 0; k < 8; ++k) a[k] += w * (float)g[j][k];
            }
        }
        for (; e < e1; ++e) {
            int s = csr[e];
            float w = __expf(leaky02(asrc[s * 4 + h] + adh));
            f16x8 g = *(const f16x8*)(H16 + (size_t)s * 128 + c);
            den += w;
#pragma unroll
            for (int k = 0; k < 8; ++k) a[k] += w * (float)g[k];
        }
        float inv = 1.f / (den + 1e-16f);
        f16x8 o;
        o[0] = (_Float16)elu1(a[0] * inv + bv0.x);
        o[1] = (_Float16)elu1(a[1] * inv + bv0.y);
        o[2] = (_Float16)elu1(a[2] * inv + bv0.z);
        o[3] = (_Float16)elu1(a[3] * inv + bv0.w);
        o[4] = (_Float16)elu1(a[4] * inv + bv1.x);
        o[5] = (_Float16)elu1(a[5] * inv + bv1.y);
        o[6] = (_Float16)elu1(a[6] * inv + bv1.z);
        o[7] = (_Float16)elu1(a[7] * inv + bv1.w);
        *(f16x8*)(out16 + (size_t)node * 128 + c) = o;
    }
}

__global__ __launch_bounds__(256, 6) void agg2_kernel(
    const _Float16* __restrict__ H16, const float* __restrict__ asrc,
    const float* __restrict__ adst, const int* __restrict__ row_ptr,
    const int* __restrict__ csr, const float* __restrict__ bias,
    float* __restrict__ out, int n) {
    int wid = (blockIdx.x * blockDim.x + threadIdx.x) >> 6;
    int lane = threadIdx.x & 63;
    int sub = lane & 15;
    int c = sub * 8;
    float4 bv0 = *(const float4*)(bias + c);
    float4 bv1 = *(const float4*)(bias + c + 4);
#pragma unroll
    for (int qq = 0; qq < 2; ++qq) {
        int node = wid * 8 + qq * 4 + (lane >> 4);
        if (node >= n) continue;
        float adh = adst[node];
        int e0 = row_ptr[node];
        int e1 = row_ptr[node + 1];
        float den = 0.f;
        float a[8];
#pragma unroll
        for (int k = 0; k < 8; ++k) a[k] = 0.f;
        int e = e0;
        for (; e + 8 <= e1; e += 8) {
            int s[8];
#pragma unroll
            for (int j = 0; j < 8; ++j) s[j] = csr[e + j];
            float l[8];
            f16x8 g[8];
#pragma unroll
            for (int j = 0; j < 8; ++j) {
                l[j] = asrc[s[j]];
                g[j] = *(const f16x8*)(H16 + (size_t)s[j] * 128 + c);
            }
#pragma unroll
            for (int j = 0; j < 8; ++j) {
                float w = __expf(leaky02(l[j] + adh));
                den += w;
#pragma unroll
                for (int k = 0; k < 8; ++k) a[k] += w * (float)g[j][k];
            }
        }
        for (; e < e1; ++e) {
            int s = csr[e];
            float w = __expf(leaky02(asrc[s] + adh));
            f16x8 g = *(const f16x8*)(H16 + (size_t)s * 128 + c);
            den += w;
#pragma unroll
            for (int k = 0; k < 8; ++k) a[k] += w * (float)g[k];
        }
        float inv = 1.f / (den + 1e-16f);
        float4 o0, o1;
        o0.x = elu1(a[0] * inv + bv0.x);
        o0.y = elu1(a[1] * inv + bv0.y);
        o0.z = elu1(a[2] * inv + bv0.z);
        o0.w = elu1(a[3] * inv + bv0.w);
        o1.x = elu1(a[4] * inv + bv1.x);
        o1.y = elu1(a[5] * inv + bv1.y);
        o1.z = elu1(a[6] * inv + bv1.z);
        o1.w = elu1(a[7] * inv + bv1.w);
        *(float4*)(out + (size_t)node * 128 + c) = o0;
        *(float4*)(out + (size_t)node * 128 + c + 4) = o1;
    }
}

// ---------------- host ----------------

extern "C" void kernel_launch(void* const* d_in, const int* in_sizes, int n_in,
                              void* d_out, int out_size, void* d_ws, size_t ws_size,
                              hipStream_t stream) {
    const float* x       = (const float*)d_in[0];
    const int*   eidx    = (const int*)d_in[1];
    const float* W1      = (const float*)d_in[2];
    const float* a_src1  = (const float*)d_in[3];
    const float* a_dst1  = (const float*)d_in[4];
    const float* b1      = (const float*)d_in[5];
    const float* W2      = (const float*)d_in[6];
    const float* a_src2  = (const float*)d_in[7];
    const float* a_dst2  = (const float*)d_in[8];
    const float* b2      = (const float*)d_in[9];
    float* out = (float*)d_out;

    const int N = in_sizes[0] / 128;  // 50000
    const int E = in_sizes[1] / 2;    // 800000
    const int* src = eidx;
    const int* dst = eidx + E;

    const int nbkt = (N + 255) >> 8;            // 196 buckets of 256 nodes
    const int ncnt = nbkt * NBLK1;              // 25088
    const int chunk = (E + NBLK1 - 1) / NBLK1;  // 6250

    // workspace carve-up (~21 MB); fp16 h1 scratch lives in d_out.
    char* w = (char*)d_ws;
    _Float16* bufH16 = (_Float16*)w; w += (size_t)N * 128 * sizeof(_Float16);
    _Float16* Wt1    = (_Float16*)w; w += (size_t)128 * 128 * sizeof(_Float16);
    _Float16* Wt2    = (_Float16*)w; w += (size_t)128 * 128 * sizeof(_Float16);
    float* asrc = (float*)w;   w += (size_t)N * 4 * sizeof(float);
    float* adst = (float*)w;   w += (size_t)N * 4 * sizeof(float);
    int* g_cnt   = (int*)w;    w += (size_t)ncnt * sizeof(int);
    int* offs    = (int*)w;    w += (size_t)(ncnt + 1) * sizeof(int);
    int* row_ptr = (int*)w;    w += (size_t)(N + 1) * sizeof(int);
    int* binned  = (int*)w;    w += (size_t)E * sizeof(int);
    int* csr     = (int*)w;    w += (size_t)(E + N) * sizeof(int);
    _Float16* bufA16 = (_Float16*)d_out;  // agg1 scratch; overwritten by agg2

    dim3 b256(256);
    const int nGemm = (N + 63) / 64;            // 782
    const int nAlpha = (N + 3) / 4;             // 12500
    // persistent agg grid: 4 waves/block, each wave = 2 node-quads (8 nodes)
    const int nAggBlocks = (N + 31) / 32;       // 1563

    // ---- CSR build: hist+prep -> scan ----
    hipLaunchKernelGGL(prep_kernel, dim3(NBLK1 + 128), b256, 0, stream, dst, g_cnt, E, chunk,
                       W1, W2, Wt1, Wt2, nbkt);
    hipLaunchKernelGGL(scan_one_kernel, dim3(1), b256, 0, stream, g_cnt, offs, ncnt);

    // ---- layer 1: gemm1 + bin scatter fused ----
    hipLaunchKernelGGL(gemm1_fused_kernel, dim3(nGemm + NBLK1), b256, 0, stream, x, Wt1,
                       bufH16, N, src, dst, offs, binned, E, chunk, nGemm, nbkt);
    hipLaunchKernelGGL(sort_alpha1_kernel, dim3(nbkt + nAlpha), b256, 0, stream, binned, offs,
                       row_ptr, csr, N, nbkt, bufH16, a_src1, a_dst1, asrc, adst);
    hipLaunchKernelGGL(agg1_kernel, dim3(nAggBlocks), b256, 0, stream, bufH16, asrc, adst,
                       row_ptr, csr, b1, bufA16, N);

    // ---- layer 2: gemm2 + alpha2 fused ----
    hipLaunchKernelGGL(gemm2_fused_kernel, dim3(nGemm), b256, 0, stream, bufA16, Wt2, bufH16, N,
                       a_src2, a_dst2, asrc, adst);
    hipLaunchKernelGGL(agg2_kernel, dim3(nAggBlocks), b256, 0, stream, bufH16, asrc, adst,
                       row_ptr, csr, b2, out, N);
}

// Round 9
// 247.294 us; speedup vs baseline: 1.3002x; 1.3002x over previous
//
#include <hip/hip_runtime.h>
#include <hip/hip_bf16.h>

// ---------------------------------------------------------------------------
// SimplifiedGATBlock: 2-layer GAT, N=50000, E=800000 (+self loops)
// R9 = R7 verbatim (253us; R8's persistent-agg + gemm2-fusion reverted:
// both aggs regressed 44->63us, FETCH 94->119MB -- more waves = L2 thrash).
// Single change: agg edge loop MLP 8 -> 16 outstanding gathers (8/4/1
// remainder tiers). More latency hiding per wave at constant wave count.
// ---------------------------------------------------------------------------

typedef _Float16 half2_t __attribute__((ext_vector_type(2)));
typedef _Float16 half4_t __attribute__((ext_vector_type(4)));
typedef _Float16 f16x8 __attribute__((ext_vector_type(8)));
typedef float f32x4 __attribute__((ext_vector_type(4)));

#define NBLK1 128      // edge chunks for binning
#define SORT_CAP 6144  // per-bucket LDS sort capacity (avg ~4340, 13+ sigma)

static __device__ __forceinline__ float leaky02(float x) {
    return x > 0.f ? x : 0.2f * x;
}
static __device__ __forceinline__ float elu1(float x) {
    return x > 0.f ? x : __expf(x) - 1.f;
}

// ---------------- prep: bucket histogram + W1/W2 fp16 transpose ------------

__global__ __launch_bounds__(256) void prep_kernel(
    const int* __restrict__ dst, int* __restrict__ g_cnt, int E, int chunk,
    const float* __restrict__ W1, const float* __restrict__ W2,
    _Float16* __restrict__ Wt1, _Float16* __restrict__ Wt2, int nbkt) {
    int b = blockIdx.x;
    int t = threadIdx.x;
    if (b < NBLK1) {
        __shared__ int h[256];
        h[t] = 0;
        __syncthreads();
        int lo = b * chunk, hi = min(E, lo + chunk);
        for (int i = lo + t; i < hi; i += 256) atomicAdd(&h[dst[i] >> 8], 1);
        __syncthreads();
        if (t < nbkt) g_cnt[t * NBLK1 + b] = h[t];
    } else {
        int idx = (b - NBLK1) * 256 + t;  // 0..32767
        int which = idx >> 14;
        int r = idx & 16383;
        int nc = r >> 7, k = r & 127;
        if (which == 0)
            Wt1[(size_t)nc * 128 + k] = (_Float16)W1[(size_t)k * 128 + nc];
        else
            Wt2[(size_t)nc * 128 + k] = (_Float16)W2[(size_t)k * 128 + nc];
    }
}

// inclusive scan of 2048-element tiles; per-tile totals to sums[]
__global__ void scan_tile_kernel(const int* __restrict__ in, int* __restrict__ out,
                                 int* __restrict__ sums, int n) {
    __shared__ int sdata[256];
    int t = threadIdx.x;
    int base = blockIdx.x * 2048 + t * 8;
    int v[8];
    int run = 0;
#pragma unroll
    for (int i = 0; i < 8; ++i) {
        int idx = base + i;
        int x = (idx < n) ? in[idx] : 0;
        run += x;
        v[i] = run;
    }
    sdata[t] = run;
    __syncthreads();
    for (int off = 1; off < 256; off <<= 1) {
        int u = (t >= off) ? sdata[t - off] : 0;
        __syncthreads();
        sdata[t] += u;
        __syncthreads();
    }
    int excl = sdata[t] - run;
#pragma unroll
    for (int i = 0; i < 8; ++i) {
        int idx = base + i;
        if (idx < n) out[idx] = v[i] + excl;
    }
    if (t == 0) sums[blockIdx.x] = sdata[255];
}

// exclusive scan of up to 64 tile sums (single wave)
__global__ void scan_sums_kernel(int* __restrict__ sums, int nb) {
    int t = threadIdx.x;  // 64 threads
    int orig = (t < nb) ? sums[t] : 0;
    int v = orig;
#pragma unroll
    for (int off = 1; off < 64; off <<= 1) {
        int u = __shfl_up(v, off, 64);
        if (t >= off) v += u;
    }
    if (t < nb) sums[t] = v - orig;  // exclusive prefix
}

// offs[i] = exclusive prefix over g_cnt, i in [0, ncnt]
__global__ void offs_kernel(const int* __restrict__ incl, const int* __restrict__ sums,
                            int* __restrict__ offs, int ncnt) {
    int i = blockIdx.x * blockDim.x + threadIdx.x;
    if (i <= ncnt) offs[i] = (i == 0) ? 0 : incl[i - 1] + sums[(i - 1) >> 11];
}

// ---------------- fused: MFMA gemm1 + bin scatter (no global atomics) ------

__global__ __launch_bounds__(256) void gemm1_fused_kernel(
    const float* __restrict__ X, const _Float16* __restrict__ Wt,
    _Float16* __restrict__ H16, int nrows, const int* __restrict__ src,
    const int* __restrict__ dst, const int* __restrict__ offs,
    int* __restrict__ binned, int E, int chunk, int nGemm, int nbkt) {
    int b = blockIdx.x;
    int t = threadIdx.x;
    if (b < nGemm) {
        int wave = t >> 6, lane = t & 63;
        int m = lane & 15, q = lane >> 4;
        int arow = b * 64 + wave * 16 + m;
        bool rowok = arow < nrows;
        const float* xr = X + (size_t)arow * 128;
        f16x8 afrag[4];
#pragma unroll
        for (int s = 0; s < 4; ++s) {
            float4 v0 = make_float4(0.f, 0.f, 0.f, 0.f);
            float4 v1 = make_float4(0.f, 0.f, 0.f, 0.f);
            if (rowok) {
                v0 = *(const float4*)(xr + s * 32 + q * 8);
                v1 = *(const float4*)(xr + s * 32 + q * 8 + 4);
            }
            f16x8 a;
            a[0] = (_Float16)v0.x; a[1] = (_Float16)v0.y;
            a[2] = (_Float16)v0.z; a[3] = (_Float16)v0.w;
            a[4] = (_Float16)v1.x; a[5] = (_Float16)v1.y;
            a[6] = (_Float16)v1.z; a[7] = (_Float16)v1.w;
            afrag[s] = a;
        }
#pragma unroll
        for (int c = 0; c < 8; ++c) {
            f32x4 acc = {0.f, 0.f, 0.f, 0.f};
#pragma unroll
            for (int s = 0; s < 4; ++s) {
                f16x8 bfrag = *(const f16x8*)(Wt + (size_t)(c * 16 + m) * 128 + s * 32 + q * 8);
                acc = __builtin_amdgcn_mfma_f32_16x16x32_f16(afrag[s], bfrag, acc, 0, 0, 0);
            }
#pragma unroll
            for (int r = 0; r < 4; ++r) {
                int orow = b * 64 + wave * 16 + q * 4 + r;
                if (orow < nrows)
                    H16[(size_t)orow * 128 + c * 16 + m] = (_Float16)acc[r];
            }
        }
    } else {
        __shared__ int cur[256];
        int sb = b - nGemm;  // 0..NBLK1-1
        if (t < nbkt) cur[t] = offs[t * NBLK1 + sb];
        __syncthreads();
        int lo = sb * chunk, hi = min(E, lo + chunk);
        for (int i = lo + t; i < hi; i += 256) {
            int d = dst[i];
            int s = src[i];
            int p = atomicAdd(&cur[d >> 8], 1);  // LDS atomic: disjoint global range
            binned[p] = ((d & 255) << 16) | s;   // N < 2^16: src fits 16 bits
        }
    }
}

// ---------------- fused: per-bucket LDS counting sort + alpha1 -------------

__global__ __launch_bounds__(256) void sort_alpha1_kernel(
    const int* __restrict__ binned, const int* __restrict__ offs,
    int* __restrict__ row_ptr, int* __restrict__ csr, int n, int nbkt,
    const _Float16* __restrict__ H16, const float* __restrict__ a_src,
    const float* __restrict__ a_dst, float* __restrict__ asrc_out,
    float* __restrict__ adst_out) {
    int b = blockIdx.x;
    int t = threadIdx.x;
    if (b < nbkt) {
        __shared__ int sorted[SORT_CAP];
        __shared__ int sdata[256];
        __shared__ int cur[256];
        int estart = offs[b * NBLK1];
        int eend = offs[(b + 1) * NBLK1];
        int node0 = b * 256;
        int nloc = min(256, n - node0);
        cur[t] = (t < nloc) ? 1 : 0;  // self-loop seed
        __syncthreads();
        for (int i = estart + t; i < eend; i += 256)
            atomicAdd(&cur[(binned[i] >> 16) & 255], 1);
        __syncthreads();
        int my = cur[t];
        sdata[t] = my;
        __syncthreads();
        for (int off = 1; off < 256; off <<= 1) {
            int u = (t >= off) ? sdata[t - off] : 0;
            __syncthreads();
            sdata[t] += u;
            __syncthreads();
        }
        int excl = sdata[t] - my;
        int total = sdata[255];
        int csr_base = estart + node0;  // earlier buckets full: +256 selfs each
        if (node0 + t <= n) row_ptr[node0 + t] = csr_base + excl;
        if (t == 0 && node0 + 256 <= n) row_ptr[node0 + 256] = csr_base + total;
        if (t < nloc) {
            if (excl < SORT_CAP) sorted[excl] = node0 + t;  // self loop
            else csr[csr_base + excl] = node0 + t;
            cur[t] = excl + 1;
        } else {
            cur[t] = 0;
        }
        __syncthreads();
        for (int i = estart + t; i < eend; i += 256) {
            int v = binned[i];
            int p = atomicAdd(&cur[(v >> 16) & 255], 1);
            int sv = v & 0xffff;
            if (p < SORT_CAP) sorted[p] = sv;
            else csr[csr_base + p] = sv;  // overflow fallback (near-impossible)
        }
        __syncthreads();
        int lim = min(total, SORT_CAP);
        for (int j = t; j < lim; j += 256) csr[csr_base + j] = sorted[j];
    } else {
        int node = (b - nbkt) * 4 + (t >> 6);
        int lane = t & 63;
        if (node >= n) return;
        int c = lane * 2;
        half2_t hv = *(const half2_t*)(H16 + (size_t)node * 128 + c);
        float2 as = *(const float2*)(a_src + c);
        float2 ad = *(const float2*)(a_dst + c);
        float hx = (float)hv.x, hy = (float)hv.y;
        float ps = hx * as.x + hy * as.y;
        float pd = hx * ad.x + hy * ad.y;
#pragma unroll
        for (int off = 1; off <= 8; off <<= 1) {
            ps += __shfl_xor(ps, off, 64);
            pd += __shfl_xor(pd, off, 64);
        }
        if ((lane & 15) == 0) {
            int h = lane >> 4;
            asrc_out[node * 4 + h] = ps;
            adst_out[node * 4 + h] = pd;
        }
    }
}

// ---------------- MFMA gemm2 (fp16 A) ----------------
__global__ __launch_bounds__(256) void gemm2_mfma_kernel(
    const _Float16* __restrict__ A16, const _Float16* __restrict__ Wt,
    _Float16* __restrict__ H16, int nrows) {
    int b = blockIdx.x;
    int t = threadIdx.x;
    int wave = t >> 6, lane = t & 63;
    int m = lane & 15, q = lane >> 4;
    int arow = b * 64 + wave * 16 + m;
    bool rowok = arow < nrows;
    const _Float16* ar = A16 + (size_t)arow * 128;
    f16x8 afrag[4];
#pragma unroll
    for (int s = 0; s < 4; ++s) {
        f16x8 a = {};
        if (rowok) a = *(const f16x8*)(ar + s * 32 + q * 8);
        afrag[s] = a;
    }
#pragma unroll
    for (int c = 0; c < 8; ++c) {
        f32x4 acc = {0.f, 0.f, 0.f, 0.f};
#pragma unroll
        for (int s = 0; s < 4; ++s) {
            f16x8 bfrag = *(const f16x8*)(Wt + (size_t)(c * 16 + m) * 128 + s * 32 + q * 8);
            acc = __builtin_amdgcn_mfma_f32_16x16x32_f16(afrag[s], bfrag, acc, 0, 0, 0);
        }
#pragma unroll
        for (int r = 0; r < 4; ++r) {
            int orow = b * 64 + wave * 16 + q * 4 + r;
            if (orow < nrows)
                H16[(size_t)orow * 128 + c * 16 + m] = (_Float16)acc[r];
        }
    }
}

__global__ void alpha2_kernel(const _Float16* __restrict__ H16, const float* __restrict__ a_src,
                              const float* __restrict__ a_dst, float* __restrict__ asrc_out,
                              float* __restrict__ adst_out, int n) {
    int wave = (blockIdx.x * blockDim.x + threadIdx.x) >> 6;
    int lane = threadIdx.x & 63;
    if (wave >= n) return;
    int c = lane * 2;
    half2_t hv = *(const half2_t*)(H16 + (size_t)wave * 128 + c);
    float2 as = *(const float2*)(a_src + c);
    float2 ad = *(const float2*)(a_dst + c);
    float hx = (float)hv.x, hy = (float)hv.y;
    float ps = hx * as.x + hy * as.y;
    float pd = hx * ad.x + hy * ad.y;
#pragma unroll
    for (int off = 1; off <= 32; off <<= 1) {
        ps += __shfl_xor(ps, off, 64);
        pd += __shfl_xor(pd, off, 64);
    }
    if (lane == 0) {
        asrc_out[wave] = ps;
        adst_out[wave] = pd;
    }
}

// ---------------- softmax aggregation ----------------
// 4 nodes/wave: 16-lane group per node; lane owns 8 channels (half8, 16B).
// R9: 16-deep main batch (16 outstanding gathers/wave) + 8/4/1 remainders.

__global__ __launch_bounds__(256) void agg1_kernel(
    const _Float16* __restrict__ H16, const float* __restrict__ asrc,
    const float* __restrict__ adst, const int* __restrict__ row_ptr,
    const int* __restrict__ csr, const float* __restrict__ bias,
    _Float16* __restrict__ out16, int n) {
    int wid = (blockIdx.x * blockDim.x + threadIdx.x) >> 6;
    int lane = threadIdx.x & 63;
    int node = wid * 4 + (lane >> 4);
    if (node >= n) return;
    int sub = lane & 15;
    int c = sub * 8;
    int h = sub >> 2;  // head = c >> 5
    float adh = adst[node * 4 + h];
    float4 bv0 = *(const float4*)(bias + c);
    float4 bv1 = *(const float4*)(bias + c + 4);
    int e0 = row_ptr[node];
    int e1 = row_ptr[node + 1];
    float den = 0.f;
    float a[8];
#pragma unroll
    for (int k = 0; k < 8; ++k) a[k] = 0.f;
    int e = e0;
    for (; e + 16 <= e1; e += 16) {
        int s[16];
#pragma unroll
        for (int j = 0; j < 16; ++j) s[j] = csr[e + j];
        float l[16];
        f16x8 g[16];
#pragma unroll
        for (int j = 0; j < 16; ++j) {
            l[j] = asrc[s[j] * 4 + h];
            g[j] = *(const f16x8*)(H16 + (size_t)s[j] * 128 + c);
        }
#pragma unroll
        for (int j = 0; j < 16; ++j) {
            float w = __expf(leaky02(l[j] + adh));
            den += w;
#pragma unroll
            for (int k = 0; k < 8; ++k) a[k] += w * (float)g[j][k];
        }
    }
    for (; e + 8 <= e1; e += 8) {
        int s[8];
#pragma unroll
        for (int j = 0; j < 8; ++j) s[j] = csr[e + j];
        float l[8];
        f16x8 g[8];
#pragma unroll
        for (int j = 0; j < 8; ++j) {
            l[j] = asrc[s[j] * 4 + h];
            g[j] = *(const f16x8*)(H16 + (size_t)s[j] * 128 + c);
        }
#pragma unroll
        for (int j = 0; j < 8; ++j) {
            float w = __expf(leaky02(l[j] + adh));
            den += w;
#pragma unroll
            for (int k = 0; k < 8; ++k) a[k] += w * (float)g[j][k];
        }
    }
    for (; e + 4 <= e1; e += 4) {
        int s[4];
#pragma unroll
        for (int j = 0; j < 4; ++j) s[j] = csr[e + j];
        float l[4];
        f16x8 g[4];
#pragma unroll
        for (int j = 0; j < 4; ++j) {
            l[j] = asrc[s[j] * 4 + h];
            g[j] = *(const f16x8*)(H16 + (size_t)s[j] * 128 + c);
        }
#pragma unroll
        for (int j = 0; j < 4; ++j) {
            float w = __expf(leaky02(l[j] + adh));
            den += w;
#pragma unroll
            for (int k = 0; k < 8; ++k) a[k] += w * (float)g[j][k];
        }
    }
    for (; e < e1; ++e) {
        int s = csr[e];
        float w = __expf(leaky02(asrc[s * 4 + h] + adh));
        f16x8 g = *(const f16x8*)(H16 + (size_t)s * 128 + c);
        den += w;
#pragma unroll
        for (int k = 0; k < 8; ++k) a[k] += w * (float)g[k];
    }
    float inv = 1.f / (den + 1e-16f);
    f16x8 o;
    o[0] = (_Float16)elu1(a[0] * inv + bv0.x);
    o[1] = (_Float16)elu1(a[1] * inv + bv0.y);
    o[2] = (_Float16)elu1(a[2] * inv + bv0.z);
    o[3] = (_Float16)elu1(a[3] * inv + bv0.w);
    o[4] = (_Float16)elu1(a[4] * inv + bv1.x);
    o[5] = (_Float16)elu1(a[5] * inv + bv1.y);
    o[6] = (_Float16)elu1(a[6] * inv + bv1.z);
    o[7] = (_Float16)elu1(a[7] * inv + bv1.w);
    *(f16x8*)(out16 + (size_t)node * 128 + c) = o;
}

__global__ __launch_bounds__(256) void agg2_kernel(
    const _Float16* __restrict__ H16, const float* __restrict__ asrc,
    const float* __restrict__ adst, const int* __restrict__ row_ptr,
    const int* __restrict__ csr, const float* __restrict__ bias,
    float* __restrict__ out, int n) {
    int wid = (blockIdx.x * blockDim.x + threadIdx.x) >> 6;
    int lane = threadIdx.x & 63;
    int node = wid * 4 + (lane >> 4);
    if (node >= n) return;
    int sub = lane & 15;
    int c = sub * 8;
    float adh = adst[node];
    float4 bv0 = *(const float4*)(bias + c);
    float4 bv1 = *(const float4*)(bias + c + 4);
    int e0 = row_ptr[node];
    int e1 = row_ptr[node + 1];
    float den = 0.f;
    float a[8];
#pragma unroll
    for (int k = 0; k < 8; ++k) a[k] = 0.f;
    int e = e0;
    for (; e + 16 <= e1; e += 16) {
        int s[16];
#pragma unroll
        for (int j = 0; j < 16; ++j) s[j] = csr[e + j];
        float l[16];
        f16x8 g[16];
#pragma unroll
        for (int j = 0; j < 16; ++j) {
            l[j] = asrc[s[j]];
            g[j] = *(const f16x8*)(H16 + (size_t)s[j] * 128 + c);
        }
#pragma unroll
        for (int j = 0; j < 16; ++j) {
            float w = __expf(leaky02(l[j] + adh));
            den += w;
#pragma unroll
            for (int k = 0; k < 8; ++k) a[k] += w * (float)g[j][k];
        }
    }
    for (; e + 8 <= e1; e += 8) {
        int s[8];
#pragma unroll
        for (int j = 0; j < 8; ++j) s[j] = csr[e + j];
        float l[8];
        f16x8 g[8];
#pragma unroll
        for (int j = 0; j < 8; ++j) {
            l[j] = asrc[s[j]];
            g[j] = *(const f16x8*)(H16 + (size_t)s[j] * 128 + c);
        }
#pragma unroll
        for (int j = 0; j < 8; ++j) {
            float w = __expf(leaky02(l[j] + adh));
            den += w;
#pragma unroll
            for (int k = 0; k < 8; ++k) a[k] += w * (float)g[j][k];
        }
    }
    for (; e + 4 <= e1; e += 4) {
        int s[4];
#pragma unroll
        for (int j = 0; j < 4; ++j) s[j] = csr[e + j];
        float l[4];
        f16x8 g[4];
#pragma unroll
        for (int j = 0; j < 4; ++j) {
            l[j] = asrc[s[j]];
            g[j] = *(const f16x8*)(H16 + (size_t)s[j] * 128 + c);
        }
#pragma unroll
        for (int j = 0; j < 4; ++j) {
            float w = __expf(leaky02(l[j] + adh));
            den += w;
#pragma unroll
            for (int k = 0; k < 8; ++k) a[k] += w * (float)g[j][k];
        }
    }
    for (; e < e1; ++e) {
        int s = csr[e];
        float w = __expf(leaky02(asrc[s] + adh));
        f16x8 g = *(const f16x8*)(H16 + (size_t)s * 128 + c);
        den += w;
#pragma unroll
        for (int k = 0; k < 8; ++k) a[k] += w * (float)g[k];
    }
    float inv = 1.f / (den + 1e-16f);
    float4 o0, o1;
    o0.x = elu1(a[0] * inv + bv0.x);
    o0.y = elu1(a[1] * inv + bv0.y);
    o0.z = elu1(a[2] * inv + bv0.z);
    o0.w = elu1(a[3] * inv + bv0.w);
    o1.x = elu1(a[4] * inv + bv1.x);
    o1.y = elu1(a[5] * inv + bv1.y);
    o1.z = elu1(a[6] * inv + bv1.z);
    o1.w = elu1(a[7] * inv + bv1.w);
    *(float4*)(out + (size_t)node * 128 + c) = o0;
    *(float4*)(out + (size_t)node * 128 + c + 4) = o1;
}

// ---------------- host ----------------

extern "C" void kernel_launch(void* const* d_in, const int* in_sizes, int n_in,
                              void* d_out, int out_size, void* d_ws, size_t ws_size,
                              hipStream_t stream) {
    const float* x       = (const float*)d_in[0];
    const int*   eidx    = (const int*)d_in[1];
    const float* W1      = (const float*)d_in[2];
    const float* a_src1  = (const float*)d_in[3];
    const float* a_dst1  = (const float*)d_in[4];
    const float* b1      = (const float*)d_in[5];
    const float* W2      = (const float*)d_in[6];
    const float* a_src2  = (const float*)d_in[7];
    const float* a_dst2  = (const float*)d_in[8];
    const float* b2      = (const float*)d_in[9];
    float* out = (float*)d_out;

    const int N = in_sizes[0] / 128;  // 50000
    const int E = in_sizes[1] / 2;    // 800000
    const int* src = eidx;
    const int* dst = eidx + E;

    const int nbkt = (N + 255) >> 8;            // 196 buckets of 256 nodes
    const int ncnt = nbkt * NBLK1;              // 25088
    const int chunk = (E + NBLK1 - 1) / NBLK1;  // 6250
    const int ntiles = (ncnt + 2047) / 2048;    // 13

    // workspace carve-up (~21 MB); fp16 h1 scratch lives in d_out.
    char* w = (char*)d_ws;
    _Float16* bufH16 = (_Float16*)w; w += (size_t)N * 128 * sizeof(_Float16);
    _Float16* Wt1    = (_Float16*)w; w += (size_t)128 * 128 * sizeof(_Float16);
    _Float16* Wt2    = (_Float16*)w; w += (size_t)128 * 128 * sizeof(_Float16);
    float* asrc = (float*)w;   w += (size_t)N * 4 * sizeof(float);
    float* adst = (float*)w;   w += (size_t)N * 4 * sizeof(float);
    int* g_cnt   = (int*)w;    w += (size_t)ncnt * sizeof(int);
    int* incl    = (int*)w;    w += (size_t)ncnt * sizeof(int);
    int* offs    = (int*)w;    w += (size_t)(ncnt + 1) * sizeof(int);
    int* sums    = (int*)w;    w += 64 * sizeof(int);
    int* row_ptr = (int*)w;    w += (size_t)(N + 1) * sizeof(int);
    int* binned  = (int*)w;    w += (size_t)E * sizeof(int);
    int* csr     = (int*)w;    w += (size_t)(E + N) * sizeof(int);
    _Float16* bufA16 = (_Float16*)d_out;  // agg1 scratch; overwritten by agg2

    dim3 b256(256);
    const int nGemm = (N + 63) / 64;            // 782
    const int nAlpha = (N + 3) / 4;             // 12500
    dim3 gAgg((((N + 3) / 4) + 3) / 4);         // 4 nodes/wave, 4 waves/block

    // ---- CSR build: hist -> scan -> offs ----
    hipLaunchKernelGGL(prep_kernel, dim3(NBLK1 + 128), b256, 0, stream, dst, g_cnt, E, chunk,
                       W1, W2, Wt1, Wt2, nbkt);
    hipLaunchKernelGGL(scan_tile_kernel, dim3(ntiles), b256, 0, stream, g_cnt, incl, sums, ncnt);
    hipLaunchKernelGGL(scan_sums_kernel, dim3(1), dim3(64), 0, stream, sums, ntiles);
    hipLaunchKernelGGL(offs_kernel, dim3((ncnt + 256) / 256 + 1), b256, 0, stream, incl, sums,
                       offs, ncnt);

    // ---- layer 1: gemm1 + bin scatter fused ----
    hipLaunchKernelGGL(gemm1_fused_kernel, dim3(nGemm + NBLK1), b256, 0, stream, x, Wt1,
                       bufH16, N, src, dst, offs, binned, E, chunk, nGemm, nbkt);
    hipLaunchKernelGGL(sort_alpha1_kernel, dim3(nbkt + nAlpha), b256, 0, stream, binned, offs,
                       row_ptr, csr, N, nbkt, bufH16, a_src1, a_dst1, asrc, adst);
    hipLaunchKernelGGL(agg1_kernel, gAgg, b256, 0, stream, bufH16, asrc, adst, row_ptr, csr, b1,
                       bufA16, N);

    // ---- layer 2 ----
    hipLaunchKernelGGL(gemm2_mfma_kernel, dim3(nGemm), b256, 0, stream, bufA16, Wt2, bufH16, N);
    hipLaunchKernelGGL(alpha2_kernel, dim3(nAlpha), b256, 0, stream, bufH16, a_src2, a_dst2,
                       asrc, adst, N);
    hipLaunchKernelGGL(agg2_kernel, gAgg, b256, 0, stream, bufH16, asrc, adst, row_ptr, csr, b2,
                       out, N);
}